// Round 1
// baseline (511.615 us; speedup 1.0000x reference)
//
#include <hip/hip_runtime.h>

// Lyapunov spectrum via chunked QR scan with warm-up re-convergence.
// inp: (T=4096, 9, B=2048) fp32.  out: (3, B) fp32.
// Lya[c,b] = (sum_k log ||beta_c(k,b)||) / (T*dt)  -- linear in the per-step
// log-norms, so C chunks compute partial sums in parallel; each non-zero chunk
// warm-starts Q=I at chunk_start-WARM and lets the contracting GS dynamics
// re-converge Q to fp32 precision (gap ~0.31/step, e^{-0.31*64} ~ 2e-9).

constexpr int T_STEPS = 4096;
constexpr int BATCH   = 2048;
constexpr int NCHUNK  = 16;
constexpr int KSEG    = T_STEPS / NCHUNK;  // 256
constexpr int WARM    = 64;

__device__ __forceinline__ void lya_step(const float J[9], float Q[9], float d[3]) {
    // M = J * Q  (per-batch 3x3 matmul), M[i*3+j]
    float M[9];
#pragma unroll
    for (int i = 0; i < 3; ++i) {
#pragma unroll
        for (int j = 0; j < 3; ++j) {
            M[i * 3 + j] = J[i * 3 + 0] * Q[0 * 3 + j]
                         + J[i * 3 + 1] * Q[1 * 3 + j]
                         + J[i * 3 + 2] * Q[2 * 3 + j];
        }
    }
    // Classical Gram-Schmidt exactly as reference (projections vs original cols)
    float b0x = M[0], b0y = M[3], b0z = M[6];
    float d00 = b0x * b0x + b0y * b0y + b0z * b0z;
    float inv00 = __builtin_amdgcn_rcpf(d00);

    float x1x = M[1], x1y = M[4], x1z = M[7];
    float c01 = (b0x * x1x + b0y * x1y + b0z * x1z) * inv00;
    float b1x = x1x - c01 * b0x;
    float b1y = x1y - c01 * b0y;
    float b1z = x1z - c01 * b0z;
    float d11 = b1x * b1x + b1y * b1y + b1z * b1z;
    float inv11 = __builtin_amdgcn_rcpf(d11);

    float x2x = M[2], x2y = M[5], x2z = M[8];
    float c02 = (b0x * x2x + b0y * x2y + b0z * x2z) * inv00;
    float c12 = (b1x * x2x + b1y * x2y + b1z * x2z) * inv11;
    float b2x = x2x - c02 * b0x - c12 * b1x;
    float b2y = x2y - c02 * b0y - c12 * b1y;
    float b2z = x2z - c02 * b0z - c12 * b1z;
    float d22 = b2x * b2x + b2y * b2y + b2z * b2z;

    float s0 = __builtin_amdgcn_rsqf(d00);
    float s1 = __builtin_amdgcn_rsqf(d11);
    float s2 = __builtin_amdgcn_rsqf(d22);
    Q[0] = b0x * s0; Q[3] = b0y * s0; Q[6] = b0z * s0;
    Q[1] = b1x * s1; Q[4] = b1y * s1; Q[7] = b1z * s1;
    Q[2] = b2x * s2; Q[5] = b2y * s2; Q[8] = b2z * s2;
    d[0] = d00; d[1] = d11; d[2] = d22;
}

__global__ __launch_bounds__(64) void lya_kernel(const float* __restrict__ inp,
                                                 float* __restrict__ out) {
    const int tid   = blockIdx.x * 64 + threadIdx.x;
    const int b     = tid & (BATCH - 1);
    const int chunk = tid / BATCH;
    const int kacc  = chunk * KSEG;
    const int s0    = (kacc >= WARM) ? (kacc - WARM) : 0;
    const int kend  = kacc + KSEG;

    float Q[9] = {1.f, 0.f, 0.f,
                  0.f, 1.f, 0.f,
                  0.f, 0.f, 1.f};
    float acc0 = 0.f, acc1 = 0.f, acc2 = 0.f;

    const float* p = inp + (size_t)s0 * 9 * BATCH + b;
    float J[9];
#pragma unroll
    for (int m = 0; m < 9; ++m) J[m] = p[(size_t)m * BATCH];
    p += (size_t)9 * BATCH;

    float d[3];

    // Warm-up: re-converge Q, discard log-norms. Prefetch k+1 (<= kacc <= 3840, in range).
    for (int k = s0; k < kacc; ++k) {
        float Jn[9];
#pragma unroll
        for (int m = 0; m < 9; ++m) Jn[m] = p[(size_t)m * BATCH];
        p += (size_t)9 * BATCH;
        lya_step(J, Q, d);
#pragma unroll
        for (int m = 0; m < 9; ++m) J[m] = Jn[m];
    }

    // Accumulation loop, last iteration peeled (no OOB prefetch).
    for (int k = kacc; k < kend - 1; ++k) {
        float Jn[9];
#pragma unroll
        for (int m = 0; m < 9; ++m) Jn[m] = p[(size_t)m * BATCH];
        p += (size_t)9 * BATCH;
        lya_step(J, Q, d);
        acc0 += __log2f(d[0]);
        acc1 += __log2f(d[1]);
        acc2 += __log2f(d[2]);
#pragma unroll
        for (int m = 0; m < 9; ++m) J[m] = Jn[m];
    }
    lya_step(J, Q, d);
    acc0 += __log2f(d[0]);
    acc1 += __log2f(d[1]);
    acc2 += __log2f(d[2]);

    // log||b|| = 0.5*ln2*log2(d);  Lya = sum / (T*dt)
    const float scale = 0.5f * 0.69314718056f / (T_STEPS * 0.01f);
    atomicAdd(&out[0 * BATCH + b], acc0 * scale);
    atomicAdd(&out[1 * BATCH + b], acc1 * scale);
    atomicAdd(&out[2 * BATCH + b], acc2 * scale);
}

extern "C" void kernel_launch(void* const* d_in, const int* in_sizes, int n_in,
                              void* d_out, int out_size, void* d_ws, size_t ws_size,
                              hipStream_t stream) {
    const float* inp = (const float*)d_in[0];
    float* out = (float*)d_out;

    hipMemsetAsync(out, 0, (size_t)out_size * sizeof(float), stream);

    dim3 grid(NCHUNK * BATCH / 64);
    dim3 block(64);
    lya_kernel<<<grid, block, 0, stream>>>(inp, out);
}

// Round 2
// 453.250 us; speedup vs baseline: 1.1288x; 1.1288x over previous
//
#include <hip/hip_runtime.h>

// Lyapunov spectrum via chunked QR scan with warm-up re-convergence.
// inp: (T=4096, 9, B=2048) fp32.  out: (3, B) fp32.
// R2: depth-4 software-pipelined prefetch ring (hide ~900cyc HBM latency),
//     inv = rsq^2 (drop v_rcp), log2 of product-of-4 (3 logs per 4 steps).

constexpr int T_STEPS = 4096;
constexpr int BATCH   = 2048;
constexpr int NCHUNK  = 16;
constexpr int KSEG    = T_STEPS / NCHUNK;  // 256
constexpr int WARM    = 64;                // GS contraction gap ~0.31/step -> e^-20 seam error
constexpr int PF      = 4;                 // prefetch ring depth

__device__ __forceinline__ void lya_step(const float J[9], float Q[9], float d[3]) {
    // M = J * Q  (per-batch 3x3 matmul), M[i*3+j]
    float M[9];
#pragma unroll
    for (int i = 0; i < 3; ++i) {
#pragma unroll
        for (int j = 0; j < 3; ++j) {
            M[i * 3 + j] = J[i * 3 + 0] * Q[0 * 3 + j]
                         + J[i * 3 + 1] * Q[1 * 3 + j]
                         + J[i * 3 + 2] * Q[2 * 3 + j];
        }
    }
    // Classical Gram-Schmidt as in reference; 1/d derived from rsqrt (no v_rcp)
    float b0x = M[0], b0y = M[3], b0z = M[6];
    float d00 = b0x * b0x + b0y * b0y + b0z * b0z;
    float r0 = __builtin_amdgcn_rsqf(d00);
    float inv00 = r0 * r0;

    float x1x = M[1], x1y = M[4], x1z = M[7];
    float c01 = (b0x * x1x + b0y * x1y + b0z * x1z) * inv00;
    float b1x = x1x - c01 * b0x;
    float b1y = x1y - c01 * b0y;
    float b1z = x1z - c01 * b0z;
    float d11 = b1x * b1x + b1y * b1y + b1z * b1z;
    float r1 = __builtin_amdgcn_rsqf(d11);
    float inv11 = r1 * r1;

    float x2x = M[2], x2y = M[5], x2z = M[8];
    float c02 = (b0x * x2x + b0y * x2y + b0z * x2z) * inv00;
    float c12 = (b1x * x2x + b1y * x2y + b1z * x2z) * inv11;
    float b2x = x2x - c02 * b0x - c12 * b1x;
    float b2y = x2y - c02 * b0y - c12 * b1y;
    float b2z = x2z - c02 * b0z - c12 * b1z;
    float d22 = b2x * b2x + b2y * b2y + b2z * b2z;
    float r2 = __builtin_amdgcn_rsqf(d22);

    Q[0] = b0x * r0; Q[3] = b0y * r0; Q[6] = b0z * r0;
    Q[1] = b1x * r1; Q[4] = b1y * r1; Q[7] = b1z * r1;
    Q[2] = b2x * r2; Q[5] = b2y * r2; Q[8] = b2z * r2;
    d[0] = d00; d[1] = d11; d[2] = d22;
}

__global__ __launch_bounds__(64) void lya_kernel(const float* __restrict__ inp,
                                                 float* __restrict__ out) {
    const int tid   = blockIdx.x * 64 + threadIdx.x;
    const int b     = tid & (BATCH - 1);
    const int chunk = tid / BATCH;           // wave-uniform (64 | 2048)
    const int kacc  = chunk * KSEG;
    const int s0    = (kacc >= WARM) ? (kacc - WARM) : 0;
    const int kend  = kacc + KSEG;
    const int nwarm = kacc - s0;             // 0 or WARM
    const int niter = kend - s0;

    const size_t row = (size_t)9 * BATCH;

    float Q[9] = {1.f, 0.f, 0.f,
                  0.f, 1.f, 0.f,
                  0.f, 0.f, 1.f};
    float acc0 = 0.f, acc1 = 0.f, acc2 = 0.f;

    // Preload the PF-deep ring with steps s0 .. s0+PF-1 (always in range:
    // s0+PF-1 <= 3840+3 < 4096).
    float Jb[PF][9];
#pragma unroll
    for (int r = 0; r < PF; ++r) {
        const float* p = inp + (size_t)(s0 + r) * row + b;
#pragma unroll
        for (int m = 0; m < 9; ++m) Jb[r][m] = p[(size_t)m * BATCH];
    }

    float d[3];

    // Warm-up: re-converge Q, discard log-norms. Prefetch step i+PF into the
    // slot just consumed. tp <= kacc+PF-1 < 4096, always in range.
    for (int i = 0; i < nwarm; i += PF) {
#pragma unroll
        for (int r = 0; r < PF; ++r) {
            lya_step(Jb[r], Q, d);
            const int tp = s0 + i + r + PF;
            const float* p = inp + (size_t)tp * row + b;
#pragma unroll
            for (int m = 0; m < 9; ++m) Jb[r][m] = p[(size_t)m * BATCH];
        }
    }

    // Accumulation: product-of-PF then one log2 per column.
    for (int i = nwarm; i < niter; i += PF) {
        float p0 = 1.f, p1 = 1.f, p2 = 1.f;
#pragma unroll
        for (int r = 0; r < PF; ++r) {
            lya_step(Jb[r], Q, d);
            p0 *= d[0]; p1 *= d[1]; p2 *= d[2];
            int tp = s0 + i + r + PF;
            if (tp > T_STEPS - 1) tp = T_STEPS - 1;   // last chunk tail: clamp (redundant read)
            const float* p = inp + (size_t)tp * row + b;
#pragma unroll
            for (int m = 0; m < 9; ++m) Jb[r][m] = p[(size_t)m * BATCH];
        }
        acc0 += __log2f(p0);
        acc1 += __log2f(p1);
        acc2 += __log2f(p2);
    }

    // log||b|| = 0.5*ln2*log2(d);  Lya = sum / (T*dt)
    const float scale = 0.5f * 0.69314718056f / (T_STEPS * 0.01f);
    atomicAdd(&out[0 * BATCH + b], acc0 * scale);
    atomicAdd(&out[1 * BATCH + b], acc1 * scale);
    atomicAdd(&out[2 * BATCH + b], acc2 * scale);
}

extern "C" void kernel_launch(void* const* d_in, const int* in_sizes, int n_in,
                              void* d_out, int out_size, void* d_ws, size_t ws_size,
                              hipStream_t stream) {
    const float* inp = (const float*)d_in[0];
    float* out = (float*)d_out;

    hipMemsetAsync(out, 0, (size_t)out_size * sizeof(float), stream);

    dim3 grid(NCHUNK * BATCH / 64);
    dim3 block(64);
    lya_kernel<<<grid, block, 0, stream>>>(inp, out);
}

// Round 3
// 405.877 us; speedup vs baseline: 1.2605x; 1.1167x over previous
//
#include <hip/hip_runtime.h>

// Lyapunov spectrum via chunked QR scan with warm-up re-convergence.
// inp: (T=4096, 9, B=2048) fp32.  out: (3, B) fp32.
// R3: 2 batches/thread (dwordx2 loads, ILP=2 chains), NCHUNK=64, WARM=32,
//     PF=4 ring. 1024 waves (1/SIMD on all 256 CUs); per-thread chain 96 iters
//     so even worst-case per-iter latency serialization costs ~40us.

typedef float v2 __attribute__((ext_vector_type(2)));

constexpr int T_STEPS = 4096;
constexpr int BATCH   = 2048;
constexpr int NCHUNK  = 64;
constexpr int KSEG    = T_STEPS / NCHUNK;  // 64
constexpr int WARM    = 32;                // gap ~0.31/step -> e^-10 seam error
constexpr int PF      = 4;                 // prefetch ring depth (divides WARM and KSEG)

constexpr int ROWV2   = 9 * BATCH / 2;     // v2 elements per time step (9216)
constexpr int COLV2   = BATCH / 2;         // v2 elements per m column (1024)

__device__ __forceinline__ v2 rsq2(v2 x) {
    v2 r;
    r.x = __builtin_amdgcn_rsqf(x.x);
    r.y = __builtin_amdgcn_rsqf(x.y);
    return r;
}

__device__ __forceinline__ void lya_step(const v2 J[9], v2 Q[9], v2 d[3]) {
    // M = J * Q  (two independent 3x3 systems in the two v2 lanes)
    v2 M[9];
#pragma unroll
    for (int i = 0; i < 3; ++i) {
#pragma unroll
        for (int j = 0; j < 3; ++j) {
            M[i * 3 + j] = J[i * 3 + 0] * Q[0 * 3 + j]
                         + J[i * 3 + 1] * Q[1 * 3 + j]
                         + J[i * 3 + 2] * Q[2 * 3 + j];
        }
    }
    // Classical Gram-Schmidt (projections vs original cols), 1/d = rsq^2
    v2 b0x = M[0], b0y = M[3], b0z = M[6];
    v2 d00 = b0x * b0x + b0y * b0y + b0z * b0z;
    v2 r0 = rsq2(d00);
    v2 inv00 = r0 * r0;

    v2 x1x = M[1], x1y = M[4], x1z = M[7];
    v2 c01 = (b0x * x1x + b0y * x1y + b0z * x1z) * inv00;
    v2 b1x = x1x - c01 * b0x;
    v2 b1y = x1y - c01 * b0y;
    v2 b1z = x1z - c01 * b0z;
    v2 d11 = b1x * b1x + b1y * b1y + b1z * b1z;
    v2 r1 = rsq2(d11);
    v2 inv11 = r1 * r1;

    v2 x2x = M[2], x2y = M[5], x2z = M[8];
    v2 c02 = (b0x * x2x + b0y * x2y + b0z * x2z) * inv00;
    v2 c12 = (b1x * x2x + b1y * x2y + b1z * x2z) * inv11;
    v2 b2x = x2x - c02 * b0x - c12 * b1x;
    v2 b2y = x2y - c02 * b0y - c12 * b1y;
    v2 b2z = x2z - c02 * b0z - c12 * b1z;
    v2 d22 = b2x * b2x + b2y * b2y + b2z * b2z;
    v2 r2 = rsq2(d22);

    Q[0] = b0x * r0; Q[3] = b0y * r0; Q[6] = b0z * r0;
    Q[1] = b1x * r1; Q[4] = b1y * r1; Q[7] = b1z * r1;
    Q[2] = b2x * r2; Q[5] = b2y * r2; Q[8] = b2z * r2;
    d[0] = d00; d[1] = d11; d[2] = d22;
}

__global__ __launch_bounds__(256) void lya_kernel(const float* __restrict__ inp,
                                                  float* __restrict__ out) {
    const int tid   = blockIdx.x * 256 + threadIdx.x;
    const int l     = tid & (COLV2 - 1);   // thread-in-chunk, handles batches 2l, 2l+1
    const int chunk = tid >> 10;           // block-uniform (1024 threads/chunk)
    const int kacc  = chunk * KSEG;
    const int s0    = (kacc >= WARM) ? (kacc - WARM) : 0;
    const int nwarm = kacc - s0;           // 0 (chunk 0) or WARM

    const v2* __restrict__ base = (const v2*)inp;

    v2 one = {1.f, 1.f}, zero = {0.f, 0.f};
    v2 Q[9] = {one, zero, zero,
               zero, one, zero,
               zero, zero, one};
    v2 acc0 = zero, acc1 = zero, acc2 = zero;

    // Preload PF-deep ring: steps s0 .. s0+PF-1 (s0+PF-1 <= 4000+3 < 4096).
    v2 Jb[PF][9];
#pragma unroll
    for (int r = 0; r < PF; ++r) {
        const v2* p = base + (size_t)(s0 + r) * ROWV2 + l;
#pragma unroll
        for (int m = 0; m < 9; ++m) Jb[r][m] = p[(size_t)m * COLV2];
    }

    v2 d[3];

    // Warm-up: re-converge Q, discard log-norms. Prefetch t = s0+i+r+PF
    // (<= kacc+PF-1 <= 4035 < 4096, always in range).
    for (int i = 0; i < nwarm; i += PF) {
#pragma unroll
        for (int r = 0; r < PF; ++r) {
            lya_step(Jb[r], Q, d);
            const v2* p = base + (size_t)(s0 + i + r + PF) * ROWV2 + l;
#pragma unroll
            for (int m = 0; m < 9; ++m) Jb[r][m] = p[(size_t)m * COLV2];
        }
    }

    // Accumulation: product-of-PF per chain, then one log2 per chain component.
    for (int i = nwarm; i < nwarm + KSEG; i += PF) {
        v2 p0 = one, p1 = one, p2 = one;
#pragma unroll
        for (int r = 0; r < PF; ++r) {
            lya_step(Jb[r], Q, d);
            p0 *= d[0]; p1 *= d[1]; p2 *= d[2];
            int tp = s0 + i + r + PF;
            if (tp > T_STEPS - 1) tp = T_STEPS - 1;   // tail: clamped redundant read
            const v2* p = base + (size_t)tp * ROWV2 + l;
#pragma unroll
            for (int m = 0; m < 9; ++m) Jb[r][m] = p[(size_t)m * COLV2];
        }
        acc0.x += __log2f(p0.x); acc0.y += __log2f(p0.y);
        acc1.x += __log2f(p1.x); acc1.y += __log2f(p1.y);
        acc2.x += __log2f(p2.x); acc2.y += __log2f(p2.y);
    }

    // log||b|| = 0.5*ln2*log2(d);  Lya = sum / (T*dt)
    const float scale = 0.5f * 0.69314718056f / (T_STEPS * 0.01f);
    const int b0 = l * 2;
    atomicAdd(&out[0 * BATCH + b0],     acc0.x * scale);
    atomicAdd(&out[0 * BATCH + b0 + 1], acc0.y * scale);
    atomicAdd(&out[1 * BATCH + b0],     acc1.x * scale);
    atomicAdd(&out[1 * BATCH + b0 + 1], acc1.y * scale);
    atomicAdd(&out[2 * BATCH + b0],     acc2.x * scale);
    atomicAdd(&out[2 * BATCH + b0 + 1], acc2.y * scale);
}

extern "C" void kernel_launch(void* const* d_in, const int* in_sizes, int n_in,
                              void* d_out, int out_size, void* d_ws, size_t ws_size,
                              hipStream_t stream) {
    const float* inp = (const float*)d_in[0];
    float* out = (float*)d_out;

    hipMemsetAsync(out, 0, (size_t)out_size * sizeof(float), stream);

    // NCHUNK chunks x (BATCH/2) threads = 65536 threads = 256 blocks of 256.
    dim3 grid(NCHUNK * COLV2 / 256);
    dim3 block(256);
    lya_kernel<<<grid, block, 0, stream>>>(inp, out);
}